// Round 1
// baseline (331.687 us; speedup 1.0000x reference)
//
#include <hip/hip_runtime.h>
#include <hip/hip_bf16.h>

// MyAvgPool2D with H=W=56, OUT_H=OUT_W=56:
//   stride = 56 // 56 = 1
//   k      = 56 - 55*1 = 1
// => 1x1 window, stride 1 avg-pool on both axes == identity.
// The reference computes out = x exactly. So the optimal "kernel" is a
// pure device-to-device copy of 32*512*56*56 = 51,380,224 fp32 elements
// (205.5 MB each way). hipMemcpyAsync is graph-capture safe and uses the
// runtime's optimized copy path (~85% of 8 TB/s measured on MI355X).

extern "C" void kernel_launch(void* const* d_in, const int* in_sizes, int n_in,
                              void* d_out, int out_size, void* d_ws, size_t ws_size,
                              hipStream_t stream) {
    (void)n_in; (void)d_ws; (void)ws_size;
    const size_t nbytes = (size_t)out_size * sizeof(float);
    (void)in_sizes;
    hipMemcpyAsync(d_out, d_in[0], nbytes, hipMemcpyDeviceToDevice, stream);
}

// Round 2
// 324.229 us; speedup vs baseline: 1.0230x; 1.0230x over previous
//
#include <hip/hip_runtime.h>
#include <hip/hip_bf16.h>

// MyAvgPool2D(56->56): stride=1, k=1 => identity. Pure copy of
// 32*512*56*56 = 51,380,224 fp32 (205.5 MB each direction).
//
// R0 lesson: hipMemcpyAsync D2D used the SDMA/blit path (~1.24 TB/s).
// A compute-kernel float4 copy reaches ~6.3 TB/s on MI355X (m13), and the
// harness's own fillBufferAligned kernel hits 6.5 TB/s on this device.

__global__ __launch_bounds__(256) void copy_f4_kernel(
        const float4* __restrict__ src, float4* __restrict__ dst, int n4) {
    int i = blockIdx.x * blockDim.x + threadIdx.x;
    if (i < n4) {
        dst[i] = src[i];
    }
}

extern "C" void kernel_launch(void* const* d_in, const int* in_sizes, int n_in,
                              void* d_out, int out_size, void* d_ws, size_t ws_size,
                              hipStream_t stream) {
    (void)n_in; (void)in_sizes; (void)d_ws; (void)ws_size;
    const float4* src = (const float4*)d_in[0];
    float4* dst = (float4*)d_out;
    const int n4 = out_size / 4;  // 12,845,056 — out_size divisible by 4
    const int block = 256;
    const int grid = (n4 + block - 1) / block;  // 50,176 blocks
    copy_f4_kernel<<<grid, block, 0, stream>>>(src, dst, n4);
}